// Round 9
// baseline (275.343 us; speedup 1.0000x reference)
//
#include <hip/hip_runtime.h>

typedef __bf16 bf16x8 __attribute__((ext_vector_type(8)));
typedef unsigned short u16x8 __attribute__((ext_vector_type(8)));
typedef unsigned short u16x4 __attribute__((ext_vector_type(4)));
typedef float f32x4 __attribute__((ext_vector_type(4)));
typedef float f32x16 __attribute__((ext_vector_type(16)));

#define B_    8
#define N_    1024
#define DIM_  1024
#define H_    8
#define HD_   128
#define SCALE_ 0.08838834764831845f

__device__ __forceinline__ unsigned short f2bf(float x) {
  unsigned int u = __float_as_uint(x);
  u += 0x7fffu + ((u >> 16) & 1u);           // RNE
  return (unsigned short)(u >> 16);
}
__device__ __forceinline__ float bf2f(unsigned short h) {
  return __uint_as_float(((unsigned int)h) << 16);
}
__device__ __forceinline__ f32x4 mfma16(u16x8 a, u16x8 b, f32x4 c) {
  return __builtin_amdgcn_mfma_f32_16x16x32_bf16(
      __builtin_bit_cast(bf16x8, a), __builtin_bit_cast(bf16x8, b), c, 0, 0, 0);
}
__device__ __forceinline__ f32x16 mfma32(u16x8 a, u16x8 b, f32x16 c) {
  return __builtin_amdgcn_mfma_f32_32x32x16_bf16(
      __builtin_bit_cast(bf16x8, a), __builtin_bit_cast(bf16x8, b), c, 0, 0, 0);
}
__device__ __forceinline__ void gl_lds16(const void* g, void* l) {
  __builtin_amdgcn_global_load_lds(
      (const __attribute__((address_space(1))) unsigned int*)g,
      (__attribute__((address_space(3))) unsigned int*)l, 16, 0, 0);
}
#define SBAR() do { asm volatile("" ::: "memory"); __builtin_amdgcn_s_barrier(); \
                    asm volatile("" ::: "memory"); } while (0)
#define LGKM0() do { asm volatile("s_waitcnt lgkmcnt(0)" ::: "memory"); \
                     __builtin_amdgcn_sched_barrier(0); } while (0)
#define VMC(n)  asm volatile("s_waitcnt vmcnt(" #n ")" ::: "memory")

// ---------------- workspace layout (bytes) ----------------
// per-bh strides: khi/klo/vh/vl each 256KB
#define WS_KHI   ((size_t)0)
#define WS_KLO   ((size_t)16 << 20)
#define WS_VH    ((size_t)32 << 20)
#define WS_VL    ((size_t)48 << 20)
#define WS_WIMG  ((size_t)64 << 20)
#define WS_AOIMG ((size_t)68 << 20)

// ================= merged prep kernel =================
// blocks: [0,1024) K, [1024,3072) V, [3072,3584) W
// khi per (bh): 16 tiles of 16KB: byte = key*256 + ((d*2) ^ ((key&7)<<4))
// klo per (bh): lane-packed 1KB blocks: block ((tile*4+kg)*4+t)*1024,
//               offset (l4*16+l15)*16 + sub8 -> klo[key=kg*16+l15][d=t*32+l4*8 ..+8]
// vh  per (bh): 32 tiles of 8KB: byte = (d*64 + k8*16) ^ ((d&7)<<4)
// vl  per (bh): 1KB blocks: block ((kt*4+pkg)*2+pkh)*1024,
//               offset (l5*32+l31)*16 -> vl[d=pkg*32+l31][keys pkh*16+l5*8 ..+8]
// wimg: per (n>>7,k>>5) 16KB tile: (n&127)*128 + ((hl*64+(k&31)*2) ^ (((n&127)&7)<<4))
__global__ __launch_bounds__(256)
void prep_all(const float* __restrict__ gk, const float* __restrict__ gv,
              const float* __restrict__ gw, char* __restrict__ khi_g,
              char* __restrict__ klo_g, char* __restrict__ vh_g,
              char* __restrict__ vl_g, char* __restrict__ wimg) {
  const int blk = blockIdx.x;
  const int t = threadIdx.x;
  if (blk < 1024) {                          // ---- K ----
    const int bh = blk >> 4, tile = blk & 15;
    const int bb = bh >> 3, hh = bh & 7;
    char* hbase = khi_g + (size_t)bh * 262144 + tile * 16384;
    char* lbase = klo_g + (size_t)bh * 262144;
    const float* src = gk + ((size_t)bb * N_ + tile * 64) * DIM_ + hh * HD_;
    #pragma unroll
    for (int c = 0; c < 8; ++c) {
      const int idx = t + 256 * c;
      const int key = idx >> 5, d0 = (idx & 31) * 4;
      f32x4 f = *(const f32x4*)(src + (size_t)key * DIM_ + d0);
      u16x4 h, g;
      #pragma unroll
      for (int j = 0; j < 4; ++j) {
        unsigned short hv = f2bf(f[j]);
        h[j] = hv;
        g[j] = f2bf(f[j] - bf2f(hv));
      }
      *(u16x4*)(hbase + key * 256 + ((d0 * 2) ^ ((key & 7) << 4))) = h;
      const int kg = key >> 4, l15 = key & 15;
      const int d8 = d0 >> 3, t2 = d8 >> 2, l4q = d8 & 3;
      const int sub8 = (d0 & 4) * 2;
      char* bp = lbase + (((tile * 4 + kg) * 4 + t2) << 10) + (l4q * 16 + l15) * 16 + sub8;
      *(u16x4*)bp = g;
    }
  } else if (blk < 3072) {                   // ---- V ----
    __shared__ float tile[32][132];
    const int b2 = blk - 1024;               // bh*32 + kt
    const int bh = b2 >> 5, kt = b2 & 31;
    const int bb = bh >> 3, hh = bh & 7;
    const float* src = gv + ((size_t)bb * N_ + kt * 32) * DIM_ + hh * HD_;
    #pragma unroll
    for (int c = 0; c < 4; ++c) {
      const int idx = t + 256 * c;
      const int key = idx >> 5, dq = (idx & 31) * 4;
      *(f32x4*)&tile[key][dq] = *(const f32x4*)(src + (size_t)key * DIM_ + dq);
    }
    __syncthreads();
    char* hbase = vh_g + (size_t)bh * 262144 + kt * 8192;
    char* lbase = vl_g + (size_t)bh * 262144;
    #pragma unroll
    for (int c = 0; c < 2; ++c) {
      const int oc = t + 256 * c;            // 0..511
      const int d = oc >> 2, k8 = oc & 3;
      u16x8 h, g;
      #pragma unroll
      for (int j = 0; j < 8; ++j) {
        float x = tile[k8 * 8 + j][d];
        unsigned short hv = f2bf(x);
        h[j] = hv;
        g[j] = f2bf(x - bf2f(hv));
      }
      *(u16x8*)(hbase + ((d * 64 + k8 * 16) ^ ((d & 7) << 4))) = h;
      const int pkg = d >> 5, l31 = d & 31, pkh = k8 >> 1, l5 = k8 & 1;
      char* bp = lbase + (((kt * 4 + pkg) * 2 + pkh) << 10) + (l5 * 32 + l31) * 16;
      *(u16x8*)bp = g;
    }
  } else {                                   // ---- W ----
    const int idx = (blk - 3072) * 256 + t;  // 0..131071
    const int n = idx >> 7, k0 = (idx & 127) * 8;
    const float* s = gw + (size_t)n * DIM_ + k0;
    f32x4 f0 = *(const f32x4*)s;
    f32x4 f1 = *(const f32x4*)(s + 4);
    u16x8 h, g;
    #pragma unroll
    for (int j = 0; j < 8; ++j) {
      float x = j < 4 ? f0[j] : f1[j - 4];
      unsigned short hv = f2bf(x);
      h[j] = hv;
      g[j] = f2bf(x - bf2f(hv));
    }
    const int T = (n >> 7) * 32 + (k0 >> 5);
    const int rl = n & 127, kl = k0 & 31;
    char* base = wimg + (size_t)T * 16384 + rl * 128;
    const int swz = (rl & 7) << 4;
    *(u16x8*)(base + ((kl * 2) ^ swz)) = h;
    *(u16x8*)(base + ((64 + kl * 2) ^ swz)) = g;
  }
}

// ================= attention kernel (1024 threads, 16 waves) =================
struct K1Smem {
  unsigned short p[64 * 1024];            // 131072 B
  union {
    char kb[2][16384];                    // QK: khi full-d tiles (dbuf)
    char vt[2][8192];                     // PV: vh tiles (dbuf)
    char comb[8][4096];                   // epilogue: O-combine
    struct { char pad[16384]; float partial[4][64]; float rinv[64]; } pp;
  } u;
};

__global__ __launch_bounds__(1024, 4)
void attn_kernel(const float* __restrict__ gq, const char* __restrict__ khi_g,
                 const char* __restrict__ klo_g, const char* __restrict__ vh_g,
                 const char* __restrict__ vl_g, float* __restrict__ gattn,
                 char* __restrict__ aoimg) {
  __shared__ K1Smem sm;
  const int bid = blockIdx.x;
  const int xcd = bid & 7, slot = bid >> 3;
  const int bh = xcd + 8 * (slot >> 4);
  const int qt = slot & 15;
  const int bb = bh >> 3, hh = bh & 7;

  const int tid = threadIdx.x;
  const int wid = tid >> 6, lane = tid & 63;
  const int rg = wid >> 2;                   // QK: row group (16 rows)
  const int kg = wid & 3;                    // QK: key group
  const int l15 = lane & 15, l4 = lane >> 4;
  const int prg = wid >> 3;                  // PV: 32-row half
  const int pkg = wid & 3;                   // PV: 32-d group
  const int pkh = (wid >> 2) & 1;            // PV: 16-key half
  const int l31 = lane & 31, l5 = lane >> 5;

  const char* khi_bh = khi_g + (size_t)bh * 262144;
  const char* klo_bh = klo_g + (size_t)bh * 262144;
  const char* vh_bh  = vh_g + (size_t)bh * 262144;
  const char* vl_bh  = vl_g + (size_t)bh * 262144;

  auto issueK = [&](int s) {                 // 16KB khi tile s -> kb[s&1], all 16 waves
    const char* src = khi_bh + s * 16384 + wid * 1024 + lane * 16;
    gl_lds16(src, sm.u.kb[s & 1] + wid * 1024);
  };
  auto issueV = [&](int kt) {                // 8KB vh tile kt -> vt[kt&1], waves 8..15
    const char* src = vh_bh + kt * 8192 + (wid - 8) * 1024 + lane * 16;
    gl_lds16(src, sm.u.vt[kt & 1] + (wid - 8) * 1024);
  };

  issueK(0);

  // ---------------- Q fragments (16 rows/wave, pre-scaled, hi/lo split) ----------------
  u16x8 qhi[4], qlo[4];
  {
    const int qrow = qt * 64 + rg * 16 + l15;
    const float* qp = gq + ((size_t)bb * N_ + qrow) * DIM_ + hh * HD_;
    #pragma unroll
    for (int t = 0; t < 4; ++t) {
      const int d0 = t * 32 + l4 * 8;
      f32x4 f0 = *(const f32x4*)(qp + d0);
      f32x4 f1 = *(const f32x4*)(qp + d0 + 4);
      #pragma unroll
      for (int j = 0; j < 8; ++j) {
        float x = (j < 4 ? f0[j] : f1[j - 4]) * SCALE_;
        unsigned short hi = f2bf(x);
        qhi[t][j] = hi;
        qlo[t][j] = f2bf(x - bf2f(hi));
      }
    }
  }

  issueK(1);
  VMC(1);                                    // K0 landed (K1 in flight)
  SBAR();

  // ---------------- Phase 1: S = K Q^T, 16 full-d sub-iters ----------------
  float lsum = 0.f;
  const int key16 = kg * 16 + l15;
  const int kswz = (key16 & 7) << 4;
  const int prow_i = rg * 16 + l15;
  char* const prow = (char*)sm.p + prow_i * 2048;
  const int pswz = (prow_i & 7) << 4;

  #pragma unroll 1
  for (int s = 0; s < 16; ++s) {
    if (s < 15) issueK(s + 1);               // kb[(s+1)&1]: readers done last iter
    // klo direct from L2: 4 x 1KB lane-packed blocks
    const char* kloblk = klo_bh + (((s * 4 + kg) * 4) << 10) + lane * 16;
    u16x8 klo0 = *(const u16x8*)(kloblk);
    u16x8 klo1 = *(const u16x8*)(kloblk + 1024);
    u16x8 klo2 = *(const u16x8*)(kloblk + 2048);
    u16x8 klo3 = *(const u16x8*)(kloblk + 3072);
    const char* krow = sm.u.kb[s & 1] + key16 * 256;
    u16x8 khi[4];
    #pragma unroll
    for (int t = 0; t < 4; ++t)
      khi[t] = *(const u16x8*)(krow + ((t * 64 + l4 * 16) ^ kswz));
    f32x4 a0 = {0.f, 0.f, 0.f, 0.f}, a1 = a0, a2 = a0;
    __builtin_amdgcn_s_setprio(1);
    #pragma unroll
    for (int t = 0; t < 4; ++t) {
      a0 = mfma16(khi[t], qhi[t], a0);
      a2 = mfma16(khi[t], qlo[t], a2);
    }
    a1 = mfma16(klo0, qhi[0], a1);
    a1 = mfma16(klo1, qhi[1], a1);
    a1 = mfma16(klo2, qhi[2], a1);
    a1 = mfma16(klo3, qhi[3], a1);
    __builtin_amdgcn_s_setprio(0);
    {
      const int keyb = (s * 64 + kg * 16 + l4 * 4) * 2;
      u16x4 pk;
      float ls = 0.f;
      #pragma unroll
      for (int r = 0; r < 4; ++r) {
        float sv = (a0[r] + a1[r]) + a2[r];
        sv = fminf(sv, 60.0f);
        float p = __expf(sv);
        ls += p;
        pk[r] = f2bf(p);
      }
      lsum += ls;
      *(u16x4*)(prow + (keyb ^ pswz)) = pk;
    }
    if (s < 15) VMC(0);                      // next khi tile landed
    SBAR();
  }

  // ---------------- rowsums -> partial -> rinv; V0 staged by waves 8..15 ----------------
  if (wid >= 8) issueV(0);                   // vt[0] aliases dead kb bytes
  {
    float s0 = lsum;
    s0 += __shfl_xor(s0, 16);
    s0 += __shfl_xor(s0, 32);
    if (lane < 16) sm.u.pp.partial[kg][rg * 16 + lane] = s0;
  }
  LGKM0();
  SBAR();
  if (tid < 64) {
    float t4 = sm.u.pp.partial[0][tid] + sm.u.pp.partial[1][tid] +
               sm.u.pp.partial[2][tid] + sm.u.pp.partial[3][tid];
    sm.u.pp.rinv[tid] = 1.0f / t4;
  }
  LGKM0();
  SBAR();
  // preload all rinv needed later (pp region is NOT clobbered by vt staging)
  const bool wr8 = (wid < 8);                // writers = waves 0..7 (not stagers)
  const int wrow = (wid & 7) * 8 + (lane >> 3);
  const float rvs = sm.u.pp.rinv[wrow];
  float rv16[16];
  if (pkh == 0) {
    #pragma unroll
    for (int r = 0; r < 16; ++r) {
      const int rowreg = (r & 3) + 8 * (r >> 2) + 4 * l5;
      rv16[r] = sm.u.pp.rinv[prg * 32 + rowreg];
    }
  }
  LGKM0();
  if (wid >= 8) VMC(0);                      // V0 landed (stagers wait; SBAR covers rest)
  SBAR();

  // ---------------- Phase 2: PV (32x32x16; vh LDS, vl direct L2) + attn write ----------------
  f32x16 acc = {};
  const char* pArow = (const char*)sm.p + (prg * 32 + l31) * 2048;
  const int paswz = ((prg * 32 + l31) & 7) << 4;
  const char* wprow = (const char*)sm.p + wrow * 2048;
  const int wswz = (wrow & 7) << 4;
  float* wdst = gattn + ((size_t)bh * N_ + qt * 64 + wrow) * N_ + (lane & 7) * 4;
  const int dpv = pkg * 32 + l31;
  const int voff = (dpv * 64 + pkh * 32 + l5 * 16) ^ ((dpv & 7) << 4);
  const char* vlbase = vl_bh + (((pkg * 2 + pkh)) << 10) + (l5 * 32 + l31) * 16;

  #pragma unroll 2
  for (int kt = 0; kt < 32; ++kt) {
    if (wid >= 8 && kt < 31) issueV(kt + 1);
    u16x8 vl = *(const u16x8*)(vlbase + (kt << 13));   // kt*8*1024
    u16x8 vh = *(const u16x8*)(sm.u.vt[kt & 1] + voff);
    u16x8 pa = *(const u16x8*)(pArow + ((kt * 64 + pkh * 32 + l5 * 16) ^ paswz));
    __builtin_amdgcn_s_setprio(1);
    acc = mfma32(pa, vh, acc);
    acc = mfma32(pa, vl, acc);
    __builtin_amdgcn_s_setprio(0);
    if (wr8) {                               // full-line attn write, fire-and-forget
      u16x4 pw = *(const u16x4*)(wprow + ((kt * 64 + (lane & 7) * 8) ^ wswz));
      f32x4 o;
      o[0] = bf2f(pw[0]) * rvs; o[1] = bf2f(pw[1]) * rvs;
      o[2] = bf2f(pw[2]) * rvs; o[3] = bf2f(pw[3]) * rvs;
      __builtin_nontemporal_store(o, (f32x4*)(wdst + kt * 32));
    } else if (kt < 31) {
      VMC(0);                                // stagers: next vh tile landed
    }
    SBAR();
  }

  // ---------------- O-combine across pkh halves + ao epilogue ----------------
  {
    char* cbase = sm.u.comb[prg * 4 + pkg] + lane * 64;
    if (pkh == 1) {
      #pragma unroll
      for (int q = 0; q < 4; ++q) {
        f32x4 v = {acc[q * 4], acc[q * 4 + 1], acc[q * 4 + 2], acc[q * 4 + 3]};
        *(f32x4*)(cbase + q * 16) = v;
      }
    }
    LGKM0();
    SBAR();
    if (pkh == 0) {
      #pragma unroll
      for (int q = 0; q < 4; ++q) {
        f32x4 v = *(const f32x4*)(cbase + q * 16);
        acc[q * 4] += v[0]; acc[q * 4 + 1] += v[1];
        acc[q * 4 + 2] += v[2]; acc[q * 4 + 3] += v[3];
      }
      const int col5 = hh * 4 + pkg;
      const int mt = bb * 8 + (qt >> 1);
      char* Tbase = aoimg + ((size_t)(mt * 32 + col5)) * 16384;
      const int klb = l31 * 2;
      #pragma unroll
      for (int r = 0; r < 16; ++r) {
        const int rowreg = (r & 3) + 8 * (r >> 2) + 4 * l5;
        const int rl = (qt & 1) * 64 + prg * 32 + rowreg;
        const int swz = (rl & 7) << 4;
        float val = acc[r] * rv16[r];
        unsigned short hv = f2bf(val);
        unsigned short lv = f2bf(val - bf2f(hv));
        char* rp = Tbase + rl * 128;
        __builtin_nontemporal_store(hv, (unsigned short*)(rp + (klb ^ swz)));
        __builtin_nontemporal_store(lv, (unsigned short*)(rp + ((64 + klb) ^ swz)));
      }
    }
  }
}

// ================= K2: out = ao @ W^T + b (128x128 tiles, 512 blocks) =================
struct K2Smem {
  char A[2][16384];
  char Bm[2][16384];
};

__global__ __launch_bounds__(512, 2)
void proj_kernel(const char* __restrict__ aoimg, const char* __restrict__ wimg,
                 const float* __restrict__ gbias, float* __restrict__ gout) {
  __shared__ K2Smem sm;
  const int nt = blockIdx.x & 7;             // nt = XCD (W slice L2-resident)
  const int mt = blockIdx.x >> 3;
  const int tid = threadIdx.x;
  const int wid = tid >> 6, lane = tid & 63;
  const int wr = wid >> 2, wc = wid & 3;     // wave: 64 rows x 32 cols
  const int l15 = lane & 15, l4 = lane >> 4;

  auto issue = [&](int s) {
    const char* sa = aoimg + ((size_t)(mt * 32 + s)) * 16384 + tid * 16;
    gl_lds16(sa, sm.A[s & 1] + (tid >> 6) * 1024);
    gl_lds16(sa + 8192, sm.A[s & 1] + 8192 + (tid >> 6) * 1024);
    const char* sb = wimg + ((size_t)(nt * 32 + s)) * 16384 + tid * 16;
    gl_lds16(sb, sm.Bm[s & 1] + (tid >> 6) * 1024);
    gl_lds16(sb + 8192, sm.Bm[s & 1] + 8192 + (tid >> 6) * 1024);
  };

  f32x4 acc[4][2];
  #pragma unroll
  for (int i = 0; i < 4; ++i)
    #pragma unroll
    for (int j = 0; j < 2; ++j) acc[i][j] = f32x4{0.f, 0.f, 0.f, 0.f};

  issue(0);
  VMC(0);
  SBAR();
  #pragma unroll 1
  for (int s = 0; s < 32; ++s) {
    if (s < 31) issue(s + 1);
    const char* Ab = sm.A[s & 1];
    const char* Bb = sm.Bm[s & 1];
    u16x8 ah[4], al[4], bh[2], bl[2];
    #pragma unroll
    for (int rt = 0; rt < 4; ++rt) {
      const int rl = wr * 64 + rt * 16 + l15;
      const char* rp = Ab + rl * 128;
      const int swz = (rl & 7) << 4;
      ah[rt] = *(const u16x8*)(rp + ((l4 * 16) ^ swz));
      al[rt] = *(const u16x8*)(rp + ((64 + l4 * 16) ^ swz));
    }
    #pragma unroll
    for (int ct = 0; ct < 2; ++ct) {
      const int cl = wc * 32 + ct * 16 + l15;
      const char* rp = Bb + cl * 128;
      const int swz = (cl & 7) << 4;
      bh[ct] = *(const u16x8*)(rp + ((l4 * 16) ^ swz));
      bl[ct] = *(const u16x8*)(rp + ((64 + l4 * 16) ^ swz));
    }
    __builtin_amdgcn_s_setprio(1);
    #pragma unroll
    for (int rt = 0; rt < 4; ++rt)
      #pragma unroll
      for (int ct = 0; ct < 2; ++ct)
        acc[rt][ct] = mfma16(ah[rt], bh[ct], acc[rt][ct]);
    #pragma unroll
    for (int rt = 0; rt < 4; ++rt)
      #pragma unroll
      for (int ct = 0; ct < 2; ++ct)
        acc[rt][ct] = mfma16(ah[rt], bl[ct], acc[rt][ct]);
    #pragma unroll
    for (int rt = 0; rt < 4; ++rt)
      #pragma unroll
      for (int ct = 0; ct < 2; ++ct)
        acc[rt][ct] = mfma16(al[rt], bh[ct], acc[rt][ct]);
    __builtin_amdgcn_s_setprio(0);
    LGKM0();
    if (s < 31) VMC(0);
    SBAR();
  }

  #pragma unroll
  for (int ct = 0; ct < 2; ++ct) {
    const int col = nt * 128 + wc * 32 + ct * 16 + l15;
    const float bv = gbias[col];
    #pragma unroll
    for (int rt = 0; rt < 4; ++rt) {
      float* dst = gout + (size_t)(mt * 128 + wr * 64 + rt * 16 + l4 * 4) * DIM_ + col;
      #pragma unroll
      for (int r = 0; r < 4; ++r)
        dst[(size_t)r * DIM_] = acc[rt][ct][r] + bv;
    }
  }
}

extern "C" void kernel_launch(void* const* d_in, const int* in_sizes, int n_in,
                              void* d_out, int out_size, void* d_ws, size_t ws_size,
                              hipStream_t stream) {
  const float* q    = (const float*)d_in[0];
  const float* k    = (const float*)d_in[1];
  const float* v    = (const float*)d_in[2];
  const float* W    = (const float*)d_in[3];
  const float* bias = (const float*)d_in[4];
  float* out  = (float*)d_out;
  float* attn = out + (size_t)B_ * N_ * DIM_;      // outputs: [out | attn]

  char* ws = (char*)d_ws;                          // needs 100 MB
  char* khi_g = ws + WS_KHI;
  char* klo_g = ws + WS_KLO;
  char* vh_g  = ws + WS_VH;
  char* vl_g  = ws + WS_VL;
  char* wimg  = ws + WS_WIMG;
  char* aoimg = ws + WS_AOIMG;

  prep_all<<<3584, 256, 0, stream>>>(k, v, W, khi_g, klo_g, vh_g, vl_g, wimg);
  attn_kernel<<<B_ * H_ * (N_ / 64), 1024, 0, stream>>>(q, khi_g, klo_g, vh_g, vl_g, attn, aoimg);
  proj_kernel<<<512, 512, 0, stream>>>(aoimg, wimg, bias, out);
}